// Round 11
// baseline (438.613 us; speedup 1.0000x reference)
//
#include <hip/hip_runtime.h>

// Subtractor50Bit: A - B via two's complement, N rows x 50 bits ({0,1} floats).
// out = [result (N*50 floats), borrow (N floats)].
//
// R10: asymmetric cache policy -- A cached, B streamed.
// R9 (both inputs NT) broke the session-long 2.6 TB/s cap: kernel dropped
// below the harness's 124us fill kernels (was 154.6), confirming the MALL
// model: 400MB of inputs cycling through the 256MB MALL leaves a SCATTERED
// ~51% residency whose random miss pattern wrecks DRAM row locality; NT
// loads made the read stream sequential. This round exploits the model's
// corollary: A alone (200MB) FITS in the MALL. Plain (allocating) loads for
// A -> full rep-to-rep residency with no competition (B is NT no-allocate;
// writes are no-allocate -- both verified this session). NT loads for B ->
// sequential 200MB HBM stream. Per-rep HBM traffic: 604 -> ~410MB, with A
// served at fabric BW from the Infinity Cache.
// Mechanism signature: FETCH ~205-260MB. Win: kernel ~75-100us (likely
// still hidden under the 124us fills in top-5; bench 436.8 -> ~390-410).
// Falsified if FETCH ~195-scattered or ~400 with dur >= R9 -> revert to R9,
// roofline call.
// Everything except A's load policy is byte-identical to R9.

constexpr int BITS = 50;
constexpr unsigned long long MASK50 = (1ULL << BITS) - 1ULL;

// clang-native vector: required by __builtin_nontemporal_load
// (HIP float2 is a struct); layout-identical to float2 (8B, 8B-aligned).
typedef float v2f __attribute__((ext_vector_type(2)));

__device__ inline unsigned long long shfl64(unsigned long long v, int src) {
    int lo = __shfl((int)(unsigned)(v & 0xffffffffULL), src, 64);
    int hi = __shfl((int)(unsigned)(v >> 32), src, 64);
    return ((unsigned long long)(unsigned)hi << 32) | (unsigned long long)(unsigned)lo;
}

// bit i -> bit 2i (valid for i < 32)
__device__ inline unsigned long long spread2(unsigned long long x) {
    x = (x | (x << 16)) & 0x0000FFFF0000FFFFULL;
    x = (x | (x << 8))  & 0x00FF00FF00FF00FFULL;
    x = (x | (x << 4))  & 0x0F0F0F0F0F0F0F0FULL;
    x = (x | (x << 2))  & 0x3333333333333333ULL;
    x = (x | (x << 1))  & 0x5555555555555555ULL;
    return x;
}

__global__ __launch_bounds__(256) void Subtractor50Bit_kernel(
    const float* __restrict__ A, const float* __restrict__ B,
    float* __restrict__ out, int N)
{
    const int lane = threadIdx.x & 63;
    const int wv   = threadIdx.x >> 6;
    const long long waveIdx = (long long)blockIdx.x * 4 + wv;
    const long long rowBase = waveIdx * 64;
    if (rowBase >= N) return;

    if (rowBase + 64 <= N) {
        // ---- full-wave fast path (64 rows, all lanes active) ----
        const long long eBase = rowBase * BITS;          // 3200 elements/wave
        const v2f* pa = (const v2f*)(A + eBase) + lane;
        const v2f* pb = (const v2f*)(B + eBase) + lane;

        // Phase 1: ALL loads issued first (independent, 512B/instr coalesced).
        // A: PLAIN loads -> allocates in MALL; 200MB fits entirely ->
        //    rep-to-rep residency, served at fabric BW.
        // B: NONTEMPORAL -> no MALL allocation -> sequential HBM stream.
        v2f fa[25], fb[25];
        #pragma unroll
        for (int t = 0; t < 25; ++t) fa[t] = pa[t * 64];
        #pragma unroll
        for (int t = 0; t < 25; ++t) fb[t] = __builtin_nontemporal_load(pb + t * 64);

        __builtin_amdgcn_sched_barrier(0);

        // Phase 2: ballots. Chunk t covers elements [128t, 128t+128):
        //   .x ballot = even-plane word t  (bit i = element 128t+2i)
        //   .y ballot = odd-plane  word t  (bit i = element 128t+2i+1)
        // E-words parked in lanes 0..24, O-words in lanes 32..56; others 0.
        unsigned long long wa = 0, wb = 0;
        const int  lane31 = lane & 31;
        const bool isLo   = lane < 32;
        #pragma unroll
        for (int t = 0; t < 25; ++t) {
            unsigned long long aE = __ballot(fa[t].x != 0.0f);
            unsigned long long aO = __ballot(fa[t].y != 0.0f);
            unsigned long long bE = __ballot(fb[t].x != 0.0f);
            unsigned long long bO = __ballot(fb[t].y != 0.0f);
            if (lane31 == t) {
                wa = isLo ? aE : aO;
                wb = isLo ? bE : bO;
            }
        }

        // Phase 3: per-lane row assembly; lane owns row (rowBase + lane).
        // Row's even bits = even-plane window [25*lane, 25*lane+25).
        const int p0 = 25 * lane;
        const int w0 = p0 >> 6;
        const int sh = p0 & 63;

        unsigned long long aE0 = shfl64(wa, w0);
        unsigned long long aE1 = shfl64(wa, w0 + 1);      // src>24 holds 0 (safe)
        unsigned long long aO0 = shfl64(wa, 32 + w0);
        unsigned long long aO1 = shfl64(wa, 33 + w0);
        unsigned long long bE0 = shfl64(wb, w0);
        unsigned long long bE1 = shfl64(wb, w0 + 1);
        unsigned long long bO0 = shfl64(wb, 32 + w0);
        unsigned long long bO1 = shfl64(wb, 33 + w0);

        unsigned long long evA = aE0 >> sh, odA = aO0 >> sh;
        unsigned long long evB = bE0 >> sh, odB = bO0 >> sh;
        if (sh > 39) {               // window straddles two plane words
            const int c = 64 - sh;   // in [1,24] here -> shifts well-defined
            evA |= aE1 << c; odA |= aO1 << c;
            evB |= bE1 << c; odB |= bO1 << c;
        }
        const unsigned long long M25 = (1ULL << 25) - 1ULL;
        evA &= M25; odA &= M25; evB &= M25; odB &= M25;

        unsigned long long av = spread2(evA) | (spread2(odA) << 1);
        unsigned long long bv = spread2(evB) | (spread2(odB) << 1);

        unsigned long long diff = (av - bv) & MASK50;     // A + ~B + 1 (mod 2^50)
        float borrow = (av < bv) ? 1.0f : 0.0f;           // 1 - carry_out

        // Phase 4: packed 8B stores, coalesced 512B/instr (plain stores;
        // writes are already no-allocate; NT-store measured as regression).
        unsigned long long* po = (unsigned long long*)(out + eBase);
        #pragma unroll
        for (int j = 0; j < 25; ++j) {
            int q = j * 64 + lane;            // float2 index in [0,1600)
            int r = q / 25;                   // owning local row (magic-mul)
            int k = 2 * (q - r * 25);         // bit index within row
            unsigned long long dr = shfl64(diff, r);
            unsigned long long t2 = dr >> k;
            po[q] = ((t2 & 1ULL) ? 0x000000003F800000ULL : 0ULL)
                  | ((t2 & 2ULL) ? 0x3F80000000000000ULL : 0ULL);
        }
        // borrow segment: naturally coalesced
        out[(long long)N * BITS + rowBase + lane] = borrow;
    } else {
        // ---- scalar tail path (partial wave; N%64!=0 safety net) ----
        long long r = rowBase + lane;
        if (r < N) {
            unsigned long long av = 0, bv = 0;
            for (int k = 0; k < BITS; ++k) {
                av |= (unsigned long long)(A[r * BITS + k] != 0.0f) << k;
                bv |= (unsigned long long)(B[r * BITS + k] != 0.0f) << k;
            }
            unsigned long long diff = (av - bv) & MASK50;
            for (int k = 0; k < BITS; ++k)
                out[r * BITS + k] = (float)((diff >> k) & 1ULL);
            out[(long long)N * BITS + r] = (av < bv) ? 1.0f : 0.0f;
        }
    }
}

extern "C" void kernel_launch(void* const* d_in, const int* in_sizes, int n_in,
                              void* d_out, int out_size, void* d_ws, size_t ws_size,
                              hipStream_t stream) {
    const float* A = (const float*)d_in[0];
    const float* B = (const float*)d_in[1];
    float* out = (float*)d_out;
    const int N = in_sizes[0] / BITS;          // 1,000,000

    const int waves  = (N + 63) / 64;          // one wave per 64 rows
    const int blocks = (waves + 3) / 4;        // 4 waves per 256-thread block
    Subtractor50Bit_kernel<<<blocks, 256, 0, stream>>>(A, B, out, N);
}